// Round 6
// baseline (420.511 us; speedup 1.0000x reference)
//
#include <hip/hip_runtime.h>
#include <math.h>

typedef unsigned short u16;
typedef __attribute__((ext_vector_type(8))) short    bf16x8;
typedef __attribute__((ext_vector_type(8))) unsigned short u16x8;
typedef __attribute__((ext_vector_type(4))) float    f32x4;

// Problem constants
#define NB   32        // batch
#define NC   256       // in channels
#define NO   256       // out channels
#define NH   56
#define NW   56
#define NP   3136      // H*W
#define NE   8
#define NID  64
#define HP   58        // padded rows
#define WP   64        // padded row width (aligned)

// Workspace layout (bytes)
#define WMIX_OFF   0                    // u16 [32][9][256][256] = 37,748,736 B
#define XPT_OFF    37748736             // u16 [32][58][64][256] = 60,817,408 B
#define POOL_OFF   98566144             // f32 [32][256]
#define RBUF_OFF   98598912             // f32 [32][8]

__device__ __forceinline__ u16 f2bf(float f) {
    unsigned u = __float_as_uint(f);
    unsigned r = (u + 0x7FFFu + ((u >> 16) & 1u)) >> 16;   // RNE
    return (u16)r;
}

__device__ __forceinline__ void gl_lds16(const void* g, void* l) {
    __builtin_amdgcn_global_load_lds(
        (const __attribute__((address_space(1))) unsigned int*)g,
        (__attribute__((address_space(3))) unsigned int*)l, 16, 0, 0);
}

// ---------------------------------------------------------------- kernel 0
// Zero pooled accumulators + the two border rows (h'=0,57) of xpadT.
__global__ __launch_bounds__(256) void zero_k(float* __restrict__ pooled,
                                              u16* __restrict__ xpadT) {
    int b = blockIdx.x, t = threadIdx.x;
    pooled[b * 256 + t] = 0.0f;
    u16x8 z = {0, 0, 0, 0, 0, 0, 0, 0};
    u16* r0 = xpadT + ((size_t)(b * HP + 0)) * WP * NC;
    u16* r1 = xpadT + ((size_t)(b * HP + 57)) * WP * NC;
    #pragma unroll
    for (int i = 0; i < 8; ++i) {
        *(u16x8*)&r0[(i * 256 + t) * 8] = z;
        *(u16x8*)&r1[(i * 256 + t) * 8] = z;
    }
}

// ---------------------------------------------------------------- kernel 1
// One block per (b,h): NCHW fp32 -> padded NHWC bf16 row transpose + pooling
// partial sums (computed from the LDS tile; no shuffles).
// LDS tile: u16 [64 w][32 slots of 8c], physical slot = s ^ (w>>2).
__global__ __launch_bounds__(256) void transpose_pool_k(const float* __restrict__ x,
                                                        u16* __restrict__ xpadT,
                                                        float* __restrict__ pooled) {
    __shared__ u16 tile[64 * 256];          // 32 KB
    int b = blockIdx.x / 56;
    int h = blockIdx.x % 56;
    int t = threadIdx.x;

    // ---- write phase: coalesced float4 reads along w
    int w4 = t & 15, c_sub = t >> 4;        // w4: 0..13 valid (56 w), c_sub: 0..15
    if (w4 < 14) {
        const float* xp = x + ((size_t)b * NC + c_sub) * NP + (size_t)h * NW + w4 * 4;
        #pragma unroll
        for (int it = 0; it < 16; ++it) {
            int c = it * 16 + c_sub;
            f32x4 v = *(const f32x4*)(xp + (size_t)it * 16 * NP);
            int key = w4;                    // (w>>2) for all 4 written rows
            int base = ((c >> 3) ^ key) * 8 + (c & 7);
            #pragma unroll
            for (int i = 0; i < 4; ++i)
                tile[(w4 * 4 + i) * 256 + base] = f2bf(v[i]);
        }
    }
    __syncthreads();

    // ---- global write phase: u16x8 along c, 1 KB/wave
    {
        int c8 = t & 31, whi = t >> 5;       // whi: 0..7
        u16* orow = xpadT + ((size_t)(b * HP + h + 1)) * WP * NC;
        #pragma unroll
        for (int j = 0; j < 8; ++j) {
            int wp = whi * 8 + j;
            u16x8 v = {0, 0, 0, 0, 0, 0, 0, 0};
            if (wp >= 1 && wp <= 56) {
                int w = wp - 1;
                v = *(const u16x8*)&tile[w * 256 + ((c8 ^ (w >> 2)) * 8)];
            }
            *(u16x8*)&orow[wp * NC + c8 * 8] = v;
        }
    }

    // ---- pool phase: per-thread channel sum over the 56 w of this row
    {
        int c = t;
        int s = c >> 3, sub = c & 7;
        float sum = 0.0f;
        #pragma unroll
        for (int w = 0; w < 56; ++w) {
            u16 u = tile[w * 256 + ((s ^ (w >> 2)) * 8) + sub];
            sum += __uint_as_float(((unsigned)u) << 16);
        }
        atomicAdd(&pooled[b * 256 + c], sum);
    }
}

// ---------------------------------------------------------------- kernel 2
// routing: rt = (pooled/3136) @ proj_w^T + proj_b ; sigmoid ; avgpool(8) -> r[32][8]
__global__ __launch_bounds__(64) void routing(const float* __restrict__ pooled,
                                              const float* __restrict__ proj_w,
                                              const float* __restrict__ proj_b,
                                              float* __restrict__ r) {
    __shared__ float ps[256];
    __shared__ float sg[64];
    int b = blockIdx.x, j = threadIdx.x;
    for (int i = j; i < 256; i += 64) ps[i] = pooled[b * NC + i] * (1.0f / 3136.0f);
    __syncthreads();
    float acc = proj_b[j];
    for (int c = 0; c < 256; ++c) acc += ps[c] * proj_w[j * NC + c];
    sg[j] = 1.0f / (1.0f + expf(-acc));
    __syncthreads();
    if (j < NE) {
        float s = 0.0f;
        #pragma unroll
        for (int q = 0; q < 8; ++q) s += sg[j * 8 + q];
        r[b * NE + j] = s * 0.125f;
    }
}

// ---------------------------------------------------------------- kernel 3
// wmix[b][kk][o][c] = bf16( sum_e r[b][e] * expert_w[e][o][c][kk] )
__global__ __launch_bounds__(256) void mix_w(const float* __restrict__ expert_w,
                                             const float* __restrict__ r,
                                             u16* __restrict__ wmix) {
    __shared__ float lr[256];
    int o = blockIdx.x, c = threadIdx.x;
    lr[c] = r[c];                               // 32*8 = 256
    __syncthreads();
    float w[8][9];
    #pragma unroll
    for (int e = 0; e < 8; ++e) {
        const float* p = expert_w + ((size_t)((e * NO + o) * NC + c)) * 9;
        #pragma unroll
        for (int kk = 0; kk < 9; ++kk) w[e][kk] = p[kk];
    }
    for (int b = 0; b < NB; ++b) {
        float acc[9] = {0, 0, 0, 0, 0, 0, 0, 0, 0};
        #pragma unroll
        for (int e = 0; e < 8; ++e) {
            float rv = lr[b * 8 + e];
            #pragma unroll
            for (int kk = 0; kk < 9; ++kk) acc[kk] += rv * w[e][kk];
        }
        #pragma unroll
        for (int kk = 0; kk < 9; ++kk)
            wmix[((size_t)((b * 9 + kk) * NO + o)) * NC + c] = f2bf(acc[kk]);
    }
}

// ---------------------------------------------------------------- kernel 4
// Implicit-GEMM conv. 256 threads (4 waves). Per block: b, o-tile 128,
// p-tile 224 (4 image rows). K = 9 taps x 256 c, chunked c0=64.
// A (weights): LDS double-buffer [2][128x64], staged via global_load_lds
//   ONE TAP AHEAD (prefetch rides vmcnt under the current tap's 56 MFMAs);
//   the single per-tap __syncthreads (vmcnt0+barrier) publishes it.
// B (image): 6 padded rows [384x64] staged once per c0 via global_load_lds.
// Both LDS tiles XOR-swizzled: 16B slot s of row r holds c-group s^(r&7);
// achieved by pre-swizzling the GLOBAL source (linear LDS dst, m173).
// Grid 896 = 8 XCD x 112, bijective swizzle: each XCD owns 4 consecutive b.
__global__ __launch_bounds__(256, 2) void conv_k(const u16* __restrict__ wmix,
                                                 const u16* __restrict__ xpadT,
                                                 float* __restrict__ out) {
    __shared__ u16 Bs[384 * 64];       // 48 KB
    __shared__ u16 As[2 * 128 * 64];   // 32 KB (two 16 KB tap buffers)
    char* Bsc = (char*)Bs;
    char* Asc = (char*)As;

    int tid  = threadIdx.x;
    int lane = tid & 63, wid = tid >> 6;     // wid 0..3
    int ln = lane & 15, hi = lane >> 4;

    int bid = blockIdx.x;
    int logical = (bid & 7) * 112 + (bid >> 3);
    int b   = logical / 28;
    int rem = logical % 28;
    int mt  = rem / 14, nt = rem % 14;
    int obase = mt * 128;
    int h0 = nt * 4;          // padded image row base (window rows h0..h0+5)
    int p0 = nt * 224;

    const u16* apane = wmix + (size_t)b * 9 * 65536 + (size_t)obase * 256;
    const u16* xbase = xpadT + ((size_t)(b * HP + h0)) * WP * NC;

    // staging addressing: thread t covers rows t3 + i*32, 16B slot t7;
    // global source c-group pre-swizzled with key (row&7) = (t3&7).
    int t3 = tid >> 3, t7 = tid & 7;
    int stg_src = t3 * 256 + ((t7 ^ (t3 & 7)) * 8);    // elements
    int stg_dst = tid * 16;                             // bytes (linear LDS)

    #define STAGE_B(C0) {                                                   \
        _Pragma("unroll")                                                   \
        for (int i = 0; i < 12; ++i)                                        \
            gl_lds16(xbase + (C0) + stg_src + i * 8192,                     \
                     Bsc + stg_dst + i * 4096);                             \
    }
    #define STAGE_A(KK, C0, BUF) {                                         \
        _Pragma("unroll")                                                   \
        for (int i = 0; i < 4; ++i)                                         \
            gl_lds16(apane + (KK) * 65536 + (C0) + stg_src + i * 8192,      \
                     Asc + (BUF) * 16384 + stg_dst + i * 4096);             \
    }

    // accumulators: 2 mi x 14 ni
    f32x4 acc[2][14];
    #pragma unroll
    for (int mi = 0; mi < 2; ++mi)
        #pragma unroll
        for (int ni = 0; ni < 14; ++ni) acc[mi][ni] = (f32x4){0.f, 0.f, 0.f, 0.f};

    // per-lane B row bases: p = ni*16 + ln ; rw = hr*64 + wv + 1
    int rwbase[14];
    #pragma unroll
    for (int ni = 0; ni < 14; ++ni) {
        int p  = ni * 16 + ln;
        int hr = p / 56;
        int wv = p - hr * 56;
        rwbase[ni] = hr * 64 + wv + 1;
    }
    // A fragment byte offsets within a buffer ((row&7) == (ln&7))
    int aoff[2][2];
    #pragma unroll
    for (int mi = 0; mi < 2; ++mi)
        #pragma unroll
        for (int ks = 0; ks < 2; ++ks)
            aoff[mi][ks] = (wid * 32 + mi * 16 + ln) * 128 + (((ks * 4 + hi) ^ (ln & 7)) << 4);

    // prologue: B(c0=0) + A(tap0) into buf0
    STAGE_B(0)
    STAGE_A(0, 0, 0)
    __syncthreads();

    for (int c0 = 0; c0 < 256; c0 += 64) {
        int cc = (c0 >> 6) & 1;              // tap-parity base for this c0 (9 odd)
        #pragma unroll
        for (int kk = 0; kk < 9; ++kk) {
            int cur = (cc + kk) & 1;
            // prefetch next tap's A into the other buffer (rides vmcnt)
            if (kk < 8) {
                STAGE_A(kk + 1, c0, cur ^ 1)
            } else if (c0 < 192) {
                STAGE_A(0, c0 + 64, cur ^ 1)
            }
            const int dh = kk / 3, kw = kk % 3;
            const int abase = cur * 16384;
            #pragma unroll
            for (int ks = 0; ks < 2; ++ks) {
                bf16x8 a0 = *(const bf16x8*)(Asc + abase + aoff[0][ks]);
                bf16x8 a1 = *(const bf16x8*)(Asc + abase + aoff[1][ks]);
                #pragma unroll
                for (int ni = 0; ni < 14; ++ni) {
                    int rw   = rwbase[ni] + dh * 64 + kw - 1;
                    int boff = rw * 128 + ((((ks << 2) + hi) ^ (rw & 7)) << 4);
                    bf16x8 bv = *(const bf16x8*)(Bsc + boff);
                    acc[0][ni] = __builtin_amdgcn_mfma_f32_16x16x32_bf16(a0, bv, acc[0][ni], 0, 0, 0);
                    acc[1][ni] = __builtin_amdgcn_mfma_f32_16x16x32_bf16(a1, bv, acc[1][ni], 0, 0, 0);
                }
            }
            __syncthreads();                 // publish A(next tap); readers done
        }
        if (c0 < 192) {
            STAGE_B(c0 + 64)                 // Bs free (tap-8 sync passed)
            __syncthreads();                 // publish B
        }
    }
    #undef STAGE_A
    #undef STAGE_B

    // epilogue: D col = lane&15 (p), row = (lane>>4)*4 + reg (o)
    float* op = out + ((size_t)(b * NO + obase + wid * 32)) * NP + p0;
    #pragma unroll
    for (int mi = 0; mi < 2; ++mi)
        #pragma unroll
        for (int ni = 0; ni < 14; ++ni) {
            f32x4 v = acc[mi][ni];
            int col = ni * 16 + ln;
            #pragma unroll
            for (int rg = 0; rg < 4; ++rg) {
                int row = mi * 16 + hi * 4 + rg;
                op[(size_t)row * NP + col] = v[rg];
            }
        }
}

// ---------------------------------------------------------------- launch
extern "C" void kernel_launch(void* const* d_in, const int* in_sizes, int n_in,
                              void* d_out, int out_size, void* d_ws, size_t ws_size,
                              hipStream_t stream) {
    (void)in_sizes; (void)n_in; (void)out_size; (void)ws_size;
    const float* x        = (const float*)d_in[0];
    const float* proj_w   = (const float*)d_in[1];
    const float* proj_b   = (const float*)d_in[2];
    const float* expert_w = (const float*)d_in[3];
    float* out = (float*)d_out;
    char*  ws  = (char*)d_ws;

    u16*   wmix   = (u16*)(ws + WMIX_OFF);
    u16*   xpadT  = (u16*)(ws + XPT_OFF);
    float* pooled = (float*)(ws + POOL_OFF);
    float* rbuf   = (float*)(ws + RBUF_OFF);

    zero_k<<<dim3(32), dim3(256), 0, stream>>>(pooled, xpadT);
    transpose_pool_k<<<dim3(32 * 56), dim3(256), 0, stream>>>(x, xpadT, pooled);
    routing<<<dim3(32), dim3(64), 0, stream>>>(pooled, proj_w, proj_b, rbuf);
    mix_w<<<dim3(256), dim3(256), 0, stream>>>(expert_w, rbuf, wmix);
    conv_k<<<dim3(32 * 28), dim3(256), 0, stream>>>(wmix, xpadT, out);
}

// Round 7
// 209.592 us; speedup vs baseline: 2.0063x; 2.0063x over previous
//
#include <hip/hip_runtime.h>
#include <math.h>

typedef unsigned short u16;
typedef __attribute__((ext_vector_type(8))) short    bf16x8;
typedef __attribute__((ext_vector_type(8))) unsigned short u16x8;
typedef __attribute__((ext_vector_type(4))) float    f32x4;

// Problem constants
#define NB   32        // batch
#define NC   256       // in channels
#define NO   256       // out channels
#define NH   56
#define NW   56
#define NP   3136      // H*W
#define NE   8
#define NID  64
#define HP   58        // padded rows
#define WP   64        // padded row width (aligned)

// Workspace layout (bytes)
#define WMIX_OFF   0                    // u16 [32][9][256][256] = 37,748,736 B
#define XPT_OFF    37748736             // u16 [32][58][64][256] = 60,817,408 B
#define POOL_OFF   98566144             // f32 [32][256]
#define RBUF_OFF   98598912             // f32 [32][8]

__device__ __forceinline__ u16 f2bf(float f) {
    unsigned u = __float_as_uint(f);
    unsigned r = (u + 0x7FFFu + ((u >> 16) & 1u)) >> 16;   // RNE
    return (u16)r;
}

__device__ __forceinline__ void gl_lds16(const void* g, void* l) {
    __builtin_amdgcn_global_load_lds(
        (const __attribute__((address_space(1))) unsigned int*)g,
        (__attribute__((address_space(3))) unsigned int*)l, 16, 0, 0);
}

// wave-local wait for own global_load_lds results; memory clobber keeps
// the following ds_reads below it, sched_barrier pins the schedule (rule #18).
#define VMCNT0_FENCE() { asm volatile("s_waitcnt vmcnt(0)" ::: "memory"); \
                         __builtin_amdgcn_sched_barrier(0); }

// ---------------------------------------------------------------- kernel 0
// Zero pooled accumulators + the two border rows (h'=0,57) of xpadT.
__global__ __launch_bounds__(256) void zero_k(float* __restrict__ pooled,
                                              u16* __restrict__ xpadT) {
    int b = blockIdx.x, t = threadIdx.x;
    pooled[b * 256 + t] = 0.0f;
    u16x8 z = {0, 0, 0, 0, 0, 0, 0, 0};
    u16* r0 = xpadT + ((size_t)(b * HP + 0)) * WP * NC;
    u16* r1 = xpadT + ((size_t)(b * HP + 57)) * WP * NC;
    #pragma unroll
    for (int i = 0; i < 8; ++i) {
        *(u16x8*)&r0[(i * 256 + t) * 8] = z;
        *(u16x8*)&r1[(i * 256 + t) * 8] = z;
    }
}

// ---------------------------------------------------------------- kernel 1
// One block per (b,h): NCHW fp32 -> padded NHWC bf16 row transpose + pooling
// partial sums (computed from the LDS tile; no shuffles).
// LDS tile: u16 [64 w][32 slots of 8c], physical slot = s ^ (w>>2).
__global__ __launch_bounds__(256) void transpose_pool_k(const float* __restrict__ x,
                                                        u16* __restrict__ xpadT,
                                                        float* __restrict__ pooled) {
    __shared__ u16 tile[64 * 256];          // 32 KB
    int b = blockIdx.x / 56;
    int h = blockIdx.x % 56;
    int t = threadIdx.x;

    // ---- write phase: coalesced float4 reads along w
    int w4 = t & 15, c_sub = t >> 4;        // w4: 0..13 valid (56 w), c_sub: 0..15
    if (w4 < 14) {
        const float* xp = x + ((size_t)b * NC + c_sub) * NP + (size_t)h * NW + w4 * 4;
        #pragma unroll
        for (int it = 0; it < 16; ++it) {
            int c = it * 16 + c_sub;
            f32x4 v = *(const f32x4*)(xp + (size_t)it * 16 * NP);
            int key = w4;                    // (w>>2) for all 4 written rows
            int base = ((c >> 3) ^ key) * 8 + (c & 7);
            #pragma unroll
            for (int i = 0; i < 4; ++i)
                tile[(w4 * 4 + i) * 256 + base] = f2bf(v[i]);
        }
    }
    __syncthreads();

    // ---- global write phase: u16x8 along c, 1 KB/wave
    {
        int c8 = t & 31, whi = t >> 5;       // whi: 0..7
        u16* orow = xpadT + ((size_t)(b * HP + h + 1)) * WP * NC;
        #pragma unroll
        for (int j = 0; j < 8; ++j) {
            int wp = whi * 8 + j;
            u16x8 v = {0, 0, 0, 0, 0, 0, 0, 0};
            if (wp >= 1 && wp <= 56) {
                int w = wp - 1;
                v = *(const u16x8*)&tile[w * 256 + ((c8 ^ (w >> 2)) * 8)];
            }
            *(u16x8*)&orow[wp * NC + c8 * 8] = v;
        }
    }

    // ---- pool phase: per-thread channel sum over the 56 w of this row
    {
        int c = t;
        int s = c >> 3, sub = c & 7;
        float sum = 0.0f;
        #pragma unroll
        for (int w = 0; w < 56; ++w) {
            u16 u = tile[w * 256 + ((s ^ (w >> 2)) * 8) + sub];
            sum += __uint_as_float(((unsigned)u) << 16);
        }
        atomicAdd(&pooled[b * 256 + c], sum);
    }
}

// ---------------------------------------------------------------- kernel 2
// routing: rt = (pooled/3136) @ proj_w^T + proj_b ; sigmoid ; avgpool(8) -> r[32][8]
__global__ __launch_bounds__(64) void routing(const float* __restrict__ pooled,
                                              const float* __restrict__ proj_w,
                                              const float* __restrict__ proj_b,
                                              float* __restrict__ r) {
    __shared__ float ps[256];
    __shared__ float sg[64];
    int b = blockIdx.x, j = threadIdx.x;
    for (int i = j; i < 256; i += 64) ps[i] = pooled[b * NC + i] * (1.0f / 3136.0f);
    __syncthreads();
    float acc = proj_b[j];
    for (int c = 0; c < 256; ++c) acc += ps[c] * proj_w[j * NC + c];
    sg[j] = 1.0f / (1.0f + expf(-acc));
    __syncthreads();
    if (j < NE) {
        float s = 0.0f;
        #pragma unroll
        for (int q = 0; q < 8; ++q) s += sg[j * 8 + q];
        r[b * NE + j] = s * 0.125f;
    }
}

// ---------------------------------------------------------------- kernel 3
// wmix[b][kk][o][c] = bf16( sum_e r[b][e] * expert_w[e][o][c][kk] )
__global__ __launch_bounds__(256) void mix_w(const float* __restrict__ expert_w,
                                             const float* __restrict__ r,
                                             u16* __restrict__ wmix) {
    __shared__ float lr[256];
    int o = blockIdx.x, c = threadIdx.x;
    lr[c] = r[c];                               // 32*8 = 256
    __syncthreads();
    float w[8][9];
    #pragma unroll
    for (int e = 0; e < 8; ++e) {
        const float* p = expert_w + ((size_t)((e * NO + o) * NC + c)) * 9;
        #pragma unroll
        for (int kk = 0; kk < 9; ++kk) w[e][kk] = p[kk];
    }
    for (int b = 0; b < NB; ++b) {
        float acc[9] = {0, 0, 0, 0, 0, 0, 0, 0, 0};
        #pragma unroll
        for (int e = 0; e < 8; ++e) {
            float rv = lr[b * 8 + e];
            #pragma unroll
            for (int kk = 0; kk < 9; ++kk) acc[kk] += rv * w[e][kk];
        }
        #pragma unroll
        for (int kk = 0; kk < 9; ++kk)
            wmix[((size_t)((b * 9 + kk) * NO + o)) * NC + c] = f2bf(acc[kk]);
    }
}

// ---------------------------------------------------------------- kernel 4
// Implicit-GEMM conv. 256 threads (4 waves). Per block: b, o-tile 128,
// p-tile 112 (2 image rows). K = 4 c0-chunks x 9 taps x 64 c.
// A (weights): WAVE-PRIVATE LDS slices. Wave w owns o-rows [w*32,w*32+32);
//   it double-buffers its own 4 KB tap slice via global_load_lds and waits
//   with a wave-local counted s_waitcnt vmcnt(0) (NO __syncthreads, so the
//   prefetch genuinely overlaps the current tap's 28 MFMAs).
// B (image): 4 padded rows [256x64] staged once per c0 (2 barriers per c0,
//   the only block-wide syncs in the K-loop).
// Both tiles XOR-swizzled via pre-swizzled global source (linear LDS dst):
//   16B slot s of row r holds c-group s^(r&7).
// Grid 1792 = 8 XCD x 224, bijective swizzle: each XCD owns 4 consecutive b.
__global__ __launch_bounds__(256, 2) void conv_k(const u16* __restrict__ wmix,
                                                 const u16* __restrict__ xpadT,
                                                 float* __restrict__ out) {
    __shared__ u16 Bs[256 * 64];       // 32 KB
    __shared__ u16 As[2 * 128 * 64];   // 32 KB: [buf][wave slice 32r][64 c]
    char* Bsc = (char*)Bs;
    char* Asc = (char*)As;

    int tid  = threadIdx.x;
    int lane = tid & 63, wid = tid >> 6;     // wid 0..3
    int ln = lane & 15, hi = lane >> 4;

    int bid = blockIdx.x;
    int logical = (bid & 7) * 224 + (bid >> 3);
    int b   = logical / 56;
    int rem = logical % 56;
    int mt  = rem / 28, nt = rem % 28;
    int obase = mt * 128;
    int h0 = nt * 2;          // padded image row base
    int p0 = nt * 112;

    const u16* apane = wmix + (size_t)b * 9 * 65536 + (size_t)obase * 256;
    const u16* xbase = xpadT + ((size_t)(b * HP + h0)) * WP * NC;

    // ---- B staging (block-wide): thread t covers rows t3+i*32, slot t7
    int t3 = tid >> 3, t7 = tid & 7;
    int bstg_src = t3 * 256 + ((t7 ^ (t3 & 7)) * 8);   // elements
    int bstg_dst = tid * 16;                            // bytes, linear
    #define STAGE_B(C0) {                                                   \
        _Pragma("unroll")                                                   \
        for (int i = 0; i < 8; ++i)                                         \
            gl_lds16(xbase + (C0) + bstg_src + i * 8192,                    \
                     Bsc + bstg_dst + i * 4096);                            \
    }

    // ---- A staging (wave-private): lane l covers local rows (l>>3)+i*8
    int l3 = lane >> 3, l7 = lane & 7;
    int astg_src = (wid * 32 + l3) * 256 + ((l7 ^ (l3 & 7)) * 8);  // elements
    int astg_dst = wid * 4096 + lane * 16;                          // bytes
    #define STAGE_A(KK, C0, BUF) {                                          \
        _Pragma("unroll")                                                   \
        for (int i = 0; i < 4; ++i)                                         \
            gl_lds16(apane + (KK) * 65536 + (C0) + astg_src + i * 2048,     \
                     Asc + (BUF) * 16384 + astg_dst + i * 1024);            \
    }

    // accumulators
    f32x4 acc[2][7];
    #pragma unroll
    for (int mi = 0; mi < 2; ++mi)
        #pragma unroll
        for (int ni = 0; ni < 7; ++ni) acc[mi][ni] = (f32x4){0.f, 0.f, 0.f, 0.f};

    // per-lane B row bases: p = ni*16 + ln ; rw = hr*64 + wv + 1
    int rwbase[7];
    #pragma unroll
    for (int ni = 0; ni < 7; ++ni) {
        int p  = ni * 16 + ln;
        int hr = (p >= 56) ? 1 : 0;
        int wv = p - hr * 56;
        rwbase[ni] = hr * 64 + wv + 1;
    }
    // A fragment byte offsets inside a buffer (local row = mi*16+ln, key ln&7)
    int aoff[2][2];
    #pragma unroll
    for (int mi = 0; mi < 2; ++mi)
        #pragma unroll
        for (int ks = 0; ks < 2; ++ks)
            aoff[mi][ks] = wid * 4096 + (mi * 16 + ln) * 128 +
                           (((ks * 4 + hi) ^ (ln & 7)) << 4);

    // prologue
    STAGE_B(0)
    STAGE_A(0, 0, 0)
    __syncthreads();                         // B(c0=0) + A(tap0) ready

    for (int c0 = 0; c0 < 256; c0 += 64) {
        int cc = (c0 >> 6) & 1;              // tap-0 buffer parity (9 odd)
        #pragma unroll
        for (int kk = 0; kk < 9; ++kk) {
            int cur = (cc + kk) & 1;
            // wave-private prefetch of next tap's A into the other buffer
            if (kk < 8) {
                STAGE_A(kk + 1, c0, cur ^ 1)
            } else if (c0 < 192) {
                STAGE_A(0, c0 + 64, cur ^ 1)
            }
            const int dh = kk / 3, kw = kk % 3;
            const int abase = cur * 16384;
            #pragma unroll
            for (int ks = 0; ks < 2; ++ks) {
                bf16x8 a0 = *(const bf16x8*)(Asc + abase + aoff[0][ks]);
                bf16x8 a1 = *(const bf16x8*)(Asc + abase + aoff[1][ks]);
                #pragma unroll
                for (int ni = 0; ni < 7; ++ni) {
                    int rw   = rwbase[ni] + dh * 64 + kw - 1;
                    int boff = rw * 128 + ((((ks << 2) + hi) ^ (rw & 7)) << 4);
                    bf16x8 bv = *(const bf16x8*)(Bsc + boff);
                    acc[0][ni] = __builtin_amdgcn_mfma_f32_16x16x32_bf16(a0, bv, acc[0][ni], 0, 0, 0);
                    acc[1][ni] = __builtin_amdgcn_mfma_f32_16x16x32_bf16(a1, bv, acc[1][ni], 0, 0, 0);
                }
            }
            VMCNT0_FENCE()                   // wave-local: A(next tap) landed
        }
        if (c0 < 192) {
            __syncthreads();                 // all waves done reading Bs
            STAGE_B(c0 + 64)
            __syncthreads();                 // publish B(next c0)
        }
    }
    #undef STAGE_A
    #undef STAGE_B

    // epilogue: D col = lane&15 (p), row = (lane>>4)*4 + reg (o)
    float* op = out + ((size_t)(b * NO + obase + wid * 32)) * NP + p0;
    #pragma unroll
    for (int mi = 0; mi < 2; ++mi)
        #pragma unroll
        for (int ni = 0; ni < 7; ++ni) {
            f32x4 v = acc[mi][ni];
            int col = ni * 16 + ln;
            #pragma unroll
            for (int rg = 0; rg < 4; ++rg) {
                int row = mi * 16 + hi * 4 + rg;
                op[(size_t)row * NP + col] = v[rg];
            }
        }
}

// ---------------------------------------------------------------- launch
extern "C" void kernel_launch(void* const* d_in, const int* in_sizes, int n_in,
                              void* d_out, int out_size, void* d_ws, size_t ws_size,
                              hipStream_t stream) {
    (void)in_sizes; (void)n_in; (void)out_size; (void)ws_size;
    const float* x        = (const float*)d_in[0];
    const float* proj_w   = (const float*)d_in[1];
    const float* proj_b   = (const float*)d_in[2];
    const float* expert_w = (const float*)d_in[3];
    float* out = (float*)d_out;
    char*  ws  = (char*)d_ws;

    u16*   wmix   = (u16*)(ws + WMIX_OFF);
    u16*   xpadT  = (u16*)(ws + XPT_OFF);
    float* pooled = (float*)(ws + POOL_OFF);
    float* rbuf   = (float*)(ws + RBUF_OFF);

    zero_k<<<dim3(32), dim3(256), 0, stream>>>(pooled, xpadT);
    transpose_pool_k<<<dim3(32 * 56), dim3(256), 0, stream>>>(x, xpadT, pooled);
    routing<<<dim3(32), dim3(64), 0, stream>>>(pooled, proj_w, proj_b, rbuf);
    mix_w<<<dim3(256), dim3(256), 0, stream>>>(expert_w, rbuf, wmix);
    conv_k<<<dim3(32 * 56), dim3(256), 0, stream>>>(wmix, xpadT, out);
}

// Round 8
// 199.189 us; speedup vs baseline: 2.1111x; 1.0522x over previous
//
#include <hip/hip_runtime.h>
#include <math.h>

typedef unsigned short u16;
typedef __attribute__((ext_vector_type(8))) short    bf16x8;
typedef __attribute__((ext_vector_type(8))) unsigned short u16x8;
typedef __attribute__((ext_vector_type(4))) float    f32x4;

// Problem constants
#define NB   32        // batch
#define NC   256       // in channels
#define NO   256       // out channels
#define NH   56
#define NW   56
#define NP   3136      // H*W
#define NE   8
#define NID  64
#define HP   58        // padded rows
#define WP   64        // padded row width (aligned)

// Workspace layout (bytes)
#define WMIX_OFF   0                    // u16 [32][9][256][256] = 37,748,736 B
#define XPT_OFF    37748736             // u16 [32][58][64][256] = 60,817,408 B
#define POOL_OFF   98566144             // f32 [32][256]
#define RBUF_OFF   98598912             // f32 [32][8]

__device__ __forceinline__ u16 f2bf(float f) {
    unsigned u = __float_as_uint(f);
    unsigned r = (u + 0x7FFFu + ((u >> 16) & 1u)) >> 16;   // RNE
    return (u16)r;
}

__device__ __forceinline__ void gl_lds16(const void* g, void* l) {
    __builtin_amdgcn_global_load_lds(
        (const __attribute__((address_space(1))) unsigned int*)g,
        (__attribute__((address_space(3))) unsigned int*)l, 16, 0, 0);
}

// wave-local counted wait; memory clobber orders the following ds_reads,
// sched_barrier pins the schedule (rule #18).
#define VM_WAIT(N) { asm volatile("s_waitcnt vmcnt(" #N ")" ::: "memory"); \
                     __builtin_amdgcn_sched_barrier(0); }

// ---------------------------------------------------------------- kernel 0
// Zero pooled accumulators + the two border rows (h'=0,57) of xpadT.
__global__ __launch_bounds__(256) void zero_k(float* __restrict__ pooled,
                                              u16* __restrict__ xpadT) {
    int b = blockIdx.x, t = threadIdx.x;
    pooled[b * 256 + t] = 0.0f;
    u16x8 z = {0, 0, 0, 0, 0, 0, 0, 0};
    u16* r0 = xpadT + ((size_t)(b * HP + 0)) * WP * NC;
    u16* r1 = xpadT + ((size_t)(b * HP + 57)) * WP * NC;
    #pragma unroll
    for (int i = 0; i < 8; ++i) {
        *(u16x8*)&r0[(i * 256 + t) * 8] = z;
        *(u16x8*)&r1[(i * 256 + t) * 8] = z;
    }
}

// ---------------------------------------------------------------- kernel 1
// One block per (b,h): NCHW fp32 -> padded NHWC bf16 row transpose + pooling
// partial sums (computed from the LDS tile; no shuffles).
// LDS tile: u16 [64 w][32 slots of 8c], physical slot = s ^ (w>>2).
__global__ __launch_bounds__(256) void transpose_pool_k(const float* __restrict__ x,
                                                        u16* __restrict__ xpadT,
                                                        float* __restrict__ pooled) {
    __shared__ u16 tile[64 * 256];          // 32 KB
    int b = blockIdx.x / 56;
    int h = blockIdx.x % 56;
    int t = threadIdx.x;

    // ---- write phase: coalesced float4 reads along w
    int w4 = t & 15, c_sub = t >> 4;        // w4: 0..13 valid (56 w), c_sub: 0..15
    if (w4 < 14) {
        const float* xp = x + ((size_t)b * NC + c_sub) * NP + (size_t)h * NW + w4 * 4;
        #pragma unroll
        for (int it = 0; it < 16; ++it) {
            int c = it * 16 + c_sub;
            f32x4 v = *(const f32x4*)(xp + (size_t)it * 16 * NP);
            int key = w4;                    // (w>>2) for all 4 written rows
            int base = ((c >> 3) ^ key) * 8 + (c & 7);
            #pragma unroll
            for (int i = 0; i < 4; ++i)
                tile[(w4 * 4 + i) * 256 + base] = f2bf(v[i]);
        }
    }
    __syncthreads();

    // ---- global write phase: u16x8 along c, 1 KB/wave
    {
        int c8 = t & 31, whi = t >> 5;       // whi: 0..7
        u16* orow = xpadT + ((size_t)(b * HP + h + 1)) * WP * NC;
        #pragma unroll
        for (int j = 0; j < 8; ++j) {
            int wp = whi * 8 + j;
            u16x8 v = {0, 0, 0, 0, 0, 0, 0, 0};
            if (wp >= 1 && wp <= 56) {
                int w = wp - 1;
                v = *(const u16x8*)&tile[w * 256 + ((c8 ^ (w >> 2)) * 8)];
            }
            *(u16x8*)&orow[wp * NC + c8 * 8] = v;
        }
    }

    // ---- pool phase: per-thread channel sum over the 56 w of this row
    {
        int c = t;
        int s = c >> 3, sub = c & 7;
        float sum = 0.0f;
        #pragma unroll
        for (int w = 0; w < 56; ++w) {
            u16 u = tile[w * 256 + ((s ^ (w >> 2)) * 8) + sub];
            sum += __uint_as_float(((unsigned)u) << 16);
        }
        atomicAdd(&pooled[b * 256 + c], sum);
    }
}

// ---------------------------------------------------------------- kernel 2
// routing: rt = (pooled/3136) @ proj_w^T + proj_b ; sigmoid ; avgpool(8) -> r[32][8]
__global__ __launch_bounds__(64) void routing(const float* __restrict__ pooled,
                                              const float* __restrict__ proj_w,
                                              const float* __restrict__ proj_b,
                                              float* __restrict__ r) {
    __shared__ float ps[256];
    __shared__ float sg[64];
    int b = blockIdx.x, j = threadIdx.x;
    for (int i = j; i < 256; i += 64) ps[i] = pooled[b * NC + i] * (1.0f / 3136.0f);
    __syncthreads();
    float acc = proj_b[j];
    for (int c = 0; c < 256; ++c) acc += ps[c] * proj_w[j * NC + c];
    sg[j] = 1.0f / (1.0f + expf(-acc));
    __syncthreads();
    if (j < NE) {
        float s = 0.0f;
        #pragma unroll
        for (int q = 0; q < 8; ++q) s += sg[j * 8 + q];
        r[b * NE + j] = s * 0.125f;
    }
}

// ---------------------------------------------------------------- kernel 3
// wmix[b][kk][o][c] = bf16( sum_e r[b][e] * expert_w[e][o][c][kk] )
__global__ __launch_bounds__(256) void mix_w(const float* __restrict__ expert_w,
                                             const float* __restrict__ r,
                                             u16* __restrict__ wmix) {
    __shared__ float lr[256];
    int o = blockIdx.x, c = threadIdx.x;
    lr[c] = r[c];                               // 32*8 = 256
    __syncthreads();
    float w[8][9];
    #pragma unroll
    for (int e = 0; e < 8; ++e) {
        const float* p = expert_w + ((size_t)((e * NO + o) * NC + c)) * 9;
        #pragma unroll
        for (int kk = 0; kk < 9; ++kk) w[e][kk] = p[kk];
    }
    for (int b = 0; b < NB; ++b) {
        float acc[9] = {0, 0, 0, 0, 0, 0, 0, 0, 0};
        #pragma unroll
        for (int e = 0; e < 8; ++e) {
            float rv = lr[b * 8 + e];
            #pragma unroll
            for (int kk = 0; kk < 9; ++kk) acc[kk] += rv * w[e][kk];
        }
        #pragma unroll
        for (int kk = 0; kk < 9; ++kk)
            wmix[((size_t)((b * 9 + kk) * NO + o)) * NC + c] = f2bf(acc[kk]);
    }
}

// ---------------------------------------------------------------- kernel 4
// Implicit-GEMM conv. 256 threads (4 waves). Per block: b, o-tile 128,
// p-tile 112 (2 image rows). K = 4 c0-chunks x 9 taps x 64 c.
// A (weights): WAVE-PRIVATE LDS slices, 3-buffer pipeline staged 2 TAPS
//   AHEAD via global_load_lds; waits are counted s_waitcnt vmcnt(8)
//   (4 loads/tap; the 2 newest taps stay in flight -- T4, never 0 in loop).
//   Tap kk reads buf kk%3; prefetch targets (kk+2)%3; at kk=7/8 the
//   prefetch rolls into the next c0's taps 0/1 so the c0 barrier drains
//   them and the next chunk starts hot.
// B (image): 4 padded rows [256x64] staged once per c0 (2 barriers per c0,
//   the only block-wide syncs in the K-loop).
// Both tiles XOR-swizzled via pre-swizzled global source (linear LDS dst):
//   16B slot s of row r holds c-group s^(r&7).
// Grid 1792 = 8 XCD x 224, bijective swizzle: each XCD owns 4 consecutive b.
__global__ __launch_bounds__(256, 2) void conv_k(const u16* __restrict__ wmix,
                                                 const u16* __restrict__ xpadT,
                                                 float* __restrict__ out) {
    __shared__ u16 Bs[256 * 64];       // 32 KB
    __shared__ u16 As[3 * 128 * 64];   // 48 KB: [buf][wave slice 32r][64 c]
    char* Bsc = (char*)Bs;
    char* Asc = (char*)As;

    int tid  = threadIdx.x;
    int lane = tid & 63, wid = tid >> 6;     // wid 0..3
    int ln = lane & 15, hi = lane >> 4;

    int bid = blockIdx.x;
    int logical = (bid & 7) * 224 + (bid >> 3);
    int b   = logical / 56;
    int rem = logical % 56;
    int mt  = rem / 28, nt = rem % 28;
    int obase = mt * 128;
    int h0 = nt * 2;          // padded image row base
    int p0 = nt * 112;

    const u16* apane = wmix + (size_t)b * 9 * 65536 + (size_t)obase * 256;
    const u16* xbase = xpadT + ((size_t)(b * HP + h0)) * WP * NC;

    // ---- B staging (block-wide): thread t covers rows t3+i*32, slot t7
    int t3 = tid >> 3, t7 = tid & 7;
    int bstg_src = t3 * 256 + ((t7 ^ (t3 & 7)) * 8);   // elements
    int bstg_dst = tid * 16;                            // bytes, linear
    #define STAGE_B(C0) {                                                   \
        _Pragma("unroll")                                                   \
        for (int i = 0; i < 8; ++i)                                         \
            gl_lds16(xbase + (C0) + bstg_src + i * 8192,                    \
                     Bsc + bstg_dst + i * 4096);                            \
    }

    // ---- A staging (wave-private): lane l covers local rows (l>>3)+i*8
    int l3 = lane >> 3, l7 = lane & 7;
    int astg_src = (wid * 32 + l3) * 256 + ((l7 ^ (l3 & 7)) * 8);  // elements
    int astg_dst = wid * 4096 + lane * 16;                          // bytes
    #define STAGE_A(KK, C0, BUF) {                                          \
        _Pragma("unroll")                                                   \
        for (int i = 0; i < 4; ++i)                                         \
            gl_lds16(apane + (KK) * 65536 + (C0) + astg_src + i * 2048,     \
                     Asc + (BUF) * 16384 + astg_dst + i * 1024);            \
    }

    // accumulators
    f32x4 acc[2][7];
    #pragma unroll
    for (int mi = 0; mi < 2; ++mi)
        #pragma unroll
        for (int ni = 0; ni < 7; ++ni) acc[mi][ni] = (f32x4){0.f, 0.f, 0.f, 0.f};

    // per-lane B row bases: p = ni*16 + ln ; rw = hr*64 + wv + 1
    int rwbase[7];
    #pragma unroll
    for (int ni = 0; ni < 7; ++ni) {
        int p  = ni * 16 + ln;
        int hr = (p >= 56) ? 1 : 0;
        int wv = p - hr * 56;
        rwbase[ni] = hr * 64 + wv + 1;
    }
    // A fragment byte offsets inside a buffer (local row = mi*16+ln, key ln&7)
    int aoff[2][2];
    #pragma unroll
    for (int mi = 0; mi < 2; ++mi)
        #pragma unroll
        for (int ks = 0; ks < 2; ++ks)
            aoff[mi][ks] = wid * 4096 + (mi * 16 + ln) * 128 +
                           (((ks * 4 + hi) ^ (ln & 7)) << 4);

    // prologue: B(c0=0) + A taps 0,1
    STAGE_B(0)
    STAGE_A(0, 0, 0)
    STAGE_A(1, 0, 1)
    __syncthreads();                         // drains everything

    for (int c0 = 0; c0 < 256; c0 += 64) {
        #pragma unroll
        for (int kk = 0; kk < 9; ++kk) {
            const int cur = kk % 3;
            const int nxt = (kk + 2) % 3;
            // prefetch 2 taps ahead (wave-private buffer), counted wait
            if (kk < 7) {
                STAGE_A(kk + 2, c0, nxt)
                VM_WAIT(8)
            } else if (kk == 7) {
                if (c0 < 192) { STAGE_A(0, c0 + 64, nxt) VM_WAIT(8) }
                else          { VM_WAIT(4) }
            } else {            // kk == 8
                if (c0 < 192) { STAGE_A(1, c0 + 64, nxt) VM_WAIT(8) }
                else          { VM_WAIT(0) }
            }
            const int dh = kk / 3, kw = kk % 3;
            const int abase = cur * 16384;
            #pragma unroll
            for (int ks = 0; ks < 2; ++ks) {
                bf16x8 a0 = *(const bf16x8*)(Asc + abase + aoff[0][ks]);
                bf16x8 a1 = *(const bf16x8*)(Asc + abase + aoff[1][ks]);
                #pragma unroll
                for (int ni = 0; ni < 7; ++ni) {
                    int rw   = rwbase[ni] + dh * 64 + kw - 1;
                    int boff = rw * 128 + ((((ks << 2) + hi) ^ (rw & 7)) << 4);
                    bf16x8 bv = *(const bf16x8*)(Bsc + boff);
                    acc[0][ni] = __builtin_amdgcn_mfma_f32_16x16x32_bf16(a0, bv, acc[0][ni], 0, 0, 0);
                    acc[1][ni] = __builtin_amdgcn_mfma_f32_16x16x32_bf16(a1, bv, acc[1][ni], 0, 0, 0);
                }
            }
        }
        if (c0 < 192) {
            __syncthreads();                 // all waves done reading Bs;
                                             // also drains rolled A prefetches
            STAGE_B(c0 + 64)
            __syncthreads();                 // publish B(next c0)
        }
    }
    #undef STAGE_A
    #undef STAGE_B

    // epilogue: D col = lane&15 (p), row = (lane>>4)*4 + reg (o)
    float* op = out + ((size_t)(b * NO + obase + wid * 32)) * NP + p0;
    #pragma unroll
    for (int mi = 0; mi < 2; ++mi)
        #pragma unroll
        for (int ni = 0; ni < 7; ++ni) {
            f32x4 v = acc[mi][ni];
            int col = ni * 16 + ln;
            #pragma unroll
            for (int rg = 0; rg < 4; ++rg) {
                int row = mi * 16 + hi * 4 + rg;
                op[(size_t)row * NP + col] = v[rg];
            }
        }
}

// ---------------------------------------------------------------- launch
extern "C" void kernel_launch(void* const* d_in, const int* in_sizes, int n_in,
                              void* d_out, int out_size, void* d_ws, size_t ws_size,
                              hipStream_t stream) {
    (void)in_sizes; (void)n_in; (void)out_size; (void)ws_size;
    const float* x        = (const float*)d_in[0];
    const float* proj_w   = (const float*)d_in[1];
    const float* proj_b   = (const float*)d_in[2];
    const float* expert_w = (const float*)d_in[3];
    float* out = (float*)d_out;
    char*  ws  = (char*)d_ws;

    u16*   wmix   = (u16*)(ws + WMIX_OFF);
    u16*   xpadT  = (u16*)(ws + XPT_OFF);
    float* pooled = (float*)(ws + POOL_OFF);
    float* rbuf   = (float*)(ws + RBUF_OFF);

    zero_k<<<dim3(32), dim3(256), 0, stream>>>(pooled, xpadT);
    transpose_pool_k<<<dim3(32 * 56), dim3(256), 0, stream>>>(x, xpadT, pooled);
    routing<<<dim3(32), dim3(64), 0, stream>>>(pooled, proj_w, proj_b, rbuf);
    mix_w<<<dim3(256), dim3(256), 0, stream>>>(expert_w, rbuf, wmix);
    conv_k<<<dim3(32 * 56), dim3(256), 0, stream>>>(wmix, xpadT, out);
}